// Round 1
// baseline (11563.719 us; speedup 1.0000x reference)
//
#include <hip/hip_runtime.h>
#include <hip/hip_bf16.h>

// ---------------- problem constants ----------------
#define NB 400000     // n_bonds
#define NA 100000     // n_atoms
#define AFD 133       // atom feature dim
#define BFD 147       // bond feature dim
#define HID 300       // hidden
#define NP  320       // padded hidden (output cols of every GEMM)
#define SMP 304       // sum_msgs padded cols

typedef short short8 __attribute__((ext_vector_type(8)));
typedef float f32x4 __attribute__((ext_vector_type(4)));

__device__ __forceinline__ ushort f2b(float f) {
    union { float f; unsigned u; } v; v.f = f;
    unsigned r = v.u + 0x7fffu + ((v.u >> 16) & 1u);
    return (ushort)(r >> 16);
}
__device__ __forceinline__ float b2f(ushort u) {
    union { unsigned u; float f; } v; v.u = ((unsigned)u) << 16;
    return v.f;
}

// ---------------- small prep kernels ----------------
__global__ void pad_w_k(const float* __restrict__ W, ushort* __restrict__ Wp,
                        int N, int K, int Kp) {
    int idx = blockIdx.x * 256 + threadIdx.x;
    if (idx >= NP * Kp) return;
    int n = idx / Kp, k = idx - n * Kp;
    Wp[idx] = (n < N && k < K) ? f2b(W[n * K + k]) : (ushort)0;
}

__global__ void dest_k(const int* __restrict__ b2a, const int* __restrict__ b2revb,
                       int* __restrict__ dest) {
    int b = blockIdx.x * 256 + threadIdx.x;
    if (b < NB) dest[b] = b2a[b2revb[b]];
}

// ---------------- GEMM: C = relu([self +] A @ W^T + bias) ----------------
// MODE 0: A = f_bonds fp32 [NB][BFD]          -> Cb = Hb bf16 [NB][NP]
// MODE 1: A = Mbuf bf16 [NB][NP]; self = Hb   -> Cb = Hb (in place)
// MODE 2: A = concat(f_atoms fp32 [NA][AFD], sum fp32 [NA][SMP]) -> Cf fp32 [NA][HID]
template<int MODE>
__global__ __launch_bounds__(512) void gemm_k(
    const float* __restrict__ A1, const float* __restrict__ A2,
    const ushort* __restrict__ Ab,
    const ushort* __restrict__ W, const float* __restrict__ bias,
    ushort* __restrict__ Cb, float* __restrict__ Cf,
    int Kp, int Ksteps)
{
    __shared__ ushort As[32 * 36];
    __shared__ ushort Bs[NP * 36];
    const int tid  = threadIdx.x;
    const int wave = tid >> 6, lane = tid & 63;
    const int wr = wave >> 2, wc = wave & 3;   // 2 x 4 waves
    const int g = lane >> 4, lr = lane & 15;
    const int m0 = blockIdx.x * 32;

    f32x4 acc[5];
#pragma unroll
    for (int f = 0; f < 5; ++f) acc[f] = (f32x4){0.f, 0.f, 0.f, 0.f};

    for (int ks = 0; ks < Ksteps; ++ks) {
        const int k0 = ks * 32;
        __syncthreads();
        // ---- stage A tile: 32 rows x 32 cols bf16 ----
        if (tid < 128) {
            const int row = tid >> 2, cc = (tid & 3) * 8;
            const int gm = m0 + row;
            ushort v[8];
            if (MODE == 0) {
#pragma unroll
                for (int j = 0; j < 8; ++j) {
                    int k = k0 + cc + j;
                    v[j] = (k < BFD) ? f2b(A1[(size_t)gm * BFD + k]) : (ushort)0;
                }
            } else if (MODE == 1) {
                const ushort* p = &Ab[(size_t)gm * NP + k0 + cc];
                ushort4 u0 = *(const ushort4*)p, u1 = *(const ushort4*)(p + 4);
                v[0]=u0.x; v[1]=u0.y; v[2]=u0.z; v[3]=u0.w;
                v[4]=u1.x; v[5]=u1.y; v[6]=u1.z; v[7]=u1.w;
            } else {
#pragma unroll
                for (int j = 0; j < 8; ++j) {
                    int k = k0 + cc + j;
                    float x = 0.f;
                    if (k < AFD) x = A1[(size_t)gm * AFD + k];
                    else if (k < AFD + SMP) x = A2[(size_t)gm * SMP + (k - AFD)];
                    v[j] = f2b(x);
                }
            }
            ushort* dst = &As[row * 36 + cc];
            *(ushort4*)dst       = make_ushort4(v[0], v[1], v[2], v[3]);
            *(ushort4*)(dst + 4) = make_ushort4(v[4], v[5], v[6], v[7]);
        }
        // ---- stage B tile: NP rows x 32 cols bf16 ----
        for (int idx = tid; idx < NP * 4; idx += 512) {
            const int n = idx >> 2, cc = (idx & 3) * 8;
            const ushort* p = &W[(size_t)n * Kp + k0 + cc];
            ushort4 u0 = *(const ushort4*)p, u1 = *(const ushort4*)(p + 4);
            ushort* dst = &Bs[n * 36 + cc];
            *(ushort4*)dst       = u0;
            *(ushort4*)(dst + 4) = u1;
        }
        __syncthreads();
        // ---- fragments + MFMA ----
        const ushort* ap = &As[(wr * 16 + lr) * 36 + 4 * g];
        ushort4 alo = *(const ushort4*)ap;
        ushort4 ahi = *(const ushort4*)(ap + 16);
        short8 af = {(short)alo.x, (short)alo.y, (short)alo.z, (short)alo.w,
                     (short)ahi.x, (short)ahi.y, (short)ahi.z, (short)ahi.w};
#pragma unroll
        for (int f = 0; f < 5; ++f) {
            const int col = wc * 80 + f * 16 + lr;
            const ushort* bp = &Bs[col * 36 + 4 * g];
            ushort4 blo = *(const ushort4*)bp;
            ushort4 bhi = *(const ushort4*)(bp + 16);
            short8 bfr = {(short)blo.x, (short)blo.y, (short)blo.z, (short)blo.w,
                          (short)bhi.x, (short)bhi.y, (short)bhi.z, (short)bhi.w};
            acc[f] = __builtin_amdgcn_mfma_f32_16x16x32_bf16(af, bfr, acc[f], 0, 0, 0);
        }
    }
    // ---- epilogue ----
#pragma unroll
    for (int f = 0; f < 5; ++f) {
        const int col = wc * 80 + f * 16 + lr;
        const float bv = (col < HID) ? bias[col] : 0.f;
#pragma unroll
        for (int r = 0; r < 4; ++r) {
            const int row = m0 + wr * 16 + g * 4 + r;
            float v = acc[f][r] + bv;
            if (MODE == 1) v += b2f(Cb[(size_t)row * NP + col]);
            v = fmaxf(v, 0.f);
            if (MODE == 2) {
                if (col < HID) Cf[(size_t)row * HID + col] = v;
            } else {
                Cb[(size_t)row * NP + col] = f2b(v);
            }
        }
    }
}

// ---------------- segment sum: sum[dest[b]][:] += Hb[b][:] ----------------
__global__ void seg_sum_k(const ushort* __restrict__ Hb, const int* __restrict__ dest,
                          float* __restrict__ sum) {
    int idx = blockIdx.x * 256 + threadIdx.x;
    if (idx >= NB * 38) return;
    int b = idx / 38, c = (idx - b * 38) * 8;
    int a = dest[b];
    const ushort* p = &Hb[(size_t)b * NP + c];
    ushort4 u0 = *(const ushort4*)p, u1 = *(const ushort4*)(p + 4);
    float* dst = &sum[(size_t)a * SMP + c];
    atomicAdd(dst + 0, b2f(u0.x));
    atomicAdd(dst + 1, b2f(u0.y));
    atomicAdd(dst + 2, b2f(u0.z));
    atomicAdd(dst + 3, b2f(u0.w));
    atomicAdd(dst + 4, b2f(u1.x));
    atomicAdd(dst + 5, b2f(u1.y));
    atomicAdd(dst + 6, b2f(u1.z));
    atomicAdd(dst + 7, b2f(u1.w));
}

// ---------------- Mbuf[b][:] = bf16(sum[b2a[b]][:] - Hb[b2revb[b]][:]) ----------------
__global__ void gather_k(const float* __restrict__ sum, const ushort* __restrict__ Hb,
                         const int* __restrict__ b2a, const int* __restrict__ b2revb,
                         ushort* __restrict__ Mb) {
    int idx = blockIdx.x * 256 + threadIdx.x;
    if (idx >= NB * 40) return;
    int b = idx / 40, c = (idx - b * 40) * 8;
    ushort4 o0 = make_ushort4(0, 0, 0, 0), o1 = o0;
    if (c < SMP) {
        int sa = b2a[b], rb = b2revb[b];
        const float* sp = &sum[(size_t)sa * SMP + c];
        const ushort* hp = &Hb[(size_t)rb * NP + c];
        ushort4 h0 = *(const ushort4*)hp, h1 = *(const ushort4*)(hp + 4);
        o0 = make_ushort4(f2b(sp[0] - b2f(h0.x)), f2b(sp[1] - b2f(h0.y)),
                          f2b(sp[2] - b2f(h0.z)), f2b(sp[3] - b2f(h0.w)));
        o1 = make_ushort4(f2b(sp[4] - b2f(h1.x)), f2b(sp[5] - b2f(h1.y)),
                          f2b(sp[6] - b2f(h1.z)), f2b(sp[7] - b2f(h1.w)));
    }
    ushort* dp = &Mb[(size_t)b * NP + c];
    *(ushort4*)dp       = o0;
    *(ushort4*)(dp + 4) = o1;
}

// ---------------- final: d_out H_bonds fp32 <- Hb bf16 ----------------
__global__ void conv_k(const ushort* __restrict__ Hb, float* __restrict__ out) {
    int idx = blockIdx.x * 256 + threadIdx.x;
    if (idx >= NB * 75) return;
    int b = idx / 75, c = (idx - b * 75) * 4;
    ushort4 u = *(const ushort4*)&Hb[(size_t)b * NP + c];
    float4 v = make_float4(b2f(u.x), b2f(u.y), b2f(u.z), b2f(u.w));
    *(float4*)&out[(size_t)b * HID + c] = v;
}

extern "C" void kernel_launch(void* const* d_in, const int* in_sizes, int n_in,
                              void* d_out, int out_size, void* d_ws, size_t ws_size,
                              hipStream_t stream) {
    const float* f_atoms = (const float*)d_in[0];
    const float* f_bonds = (const float*)d_in[1];
    const int*   b2a     = (const int*)d_in[2];
    const int*   b2revb  = (const int*)d_in[3];
    const float* Wi_w    = (const float*)d_in[4];
    const float* Wi_b    = (const float*)d_in[5];
    const float* Wh_w    = (const float*)d_in[6];
    const float* Wh_b    = (const float*)d_in[7];
    const float* Wo_w    = (const float*)d_in[8];
    const float* Wo_b    = (const float*)d_in[9];
    float* out = (float*)d_out;

    // workspace layout
    char* ws = (char*)d_ws;
    ushort* Hb   = (ushort*)ws;            ws += (size_t)NB * NP * 2;   // 256.0 MB
    float*  sum  = (float*)ws;             ws += (size_t)NA * SMP * 4;  // 121.6 MB
    int*    dest = (int*)ws;               ws += (size_t)NB * 4;        // 1.6 MB
    ushort* Wip  = (ushort*)ws;            ws += (size_t)NP * 160 * 2;
    ushort* Whp  = (ushort*)ws;            ws += (size_t)NP * NP * 2;
    ushort* Wop  = (ushort*)ws;            ws += (size_t)NP * 448 * 2;
    // msgs buffer lives inside d_out's H_bonds region (overwritten at the end)
    float* Hatoms = out;                   // [NA][HID]
    float* Hbonds = out + (size_t)NA * HID;
    ushort* Mbuf  = (ushort*)Hbonds;       // [NB][NP] bf16 (256 MB of 480 MB)

    // prep
    pad_w_k<<<(NP * 160 + 255) / 256, 256, 0, stream>>>(Wi_w, Wip, HID, BFD, 160);
    pad_w_k<<<(NP * NP  + 255) / 256, 256, 0, stream>>>(Wh_w, Whp, HID, HID, NP);
    pad_w_k<<<(NP * 448 + 255) / 256, 256, 0, stream>>>(Wo_w, Wop, HID, AFD + HID, 448);
    dest_k<<<(NB + 255) / 256, 256, 0, stream>>>(b2a, b2revb, dest);

    // H_bonds = relu(f_bonds @ Wi^T + bi)
    gemm_k<0><<<NB / 32, 512, 0, stream>>>(f_bonds, nullptr, nullptr, Wip, Wi_b,
                                           Hb, nullptr, 160, 5);

    for (int it = 0; it < 2; ++it) {
        hipMemsetAsync(sum, 0, (size_t)NA * SMP * 4, stream);
        seg_sum_k<<<(NB * 38 + 255) / 256, 256, 0, stream>>>(Hb, dest, sum);
        gather_k<<<(NB * 40 + 255) / 256, 256, 0, stream>>>(sum, Hb, b2a, b2revb, Mbuf);
        gemm_k<1><<<NB / 32, 512, 0, stream>>>(nullptr, nullptr, Mbuf, Whp, Wh_b,
                                               Hb, nullptr, NP, 10);
    }

    hipMemsetAsync(sum, 0, (size_t)NA * SMP * 4, stream);
    seg_sum_k<<<(NB * 38 + 255) / 256, 256, 0, stream>>>(Hb, dest, sum);

    // H_atoms = relu(concat(f_atoms, sum) @ Wo^T + bo)
    gemm_k<2><<<NA / 32, 512, 0, stream>>>(f_atoms, sum, nullptr, Wop, Wo_b,
                                           nullptr, Hatoms, 448, 14);

    // H_bonds fp32 out (overwrites Mbuf region)
    conv_k<<<(NB * 75 + 255) / 256, 256, 0, stream>>>(Hb, Hbonds);
}

// Round 2
// 1957.631 us; speedup vs baseline: 5.9070x; 5.9070x over previous
//
#include <hip/hip_runtime.h>
#include <hip/hip_bf16.h>

// ---------------- problem constants ----------------
#define NB 400000     // n_bonds
#define NA 100000     // n_atoms
#define AFD 133       // atom feature dim
#define BFD 147       // bond feature dim
#define HID 300       // hidden
#define NP  320       // padded hidden (output cols of every GEMM)
#define SMP 304       // sum_msgs padded cols
#define NT  98        // scan tiles: ceil(NA/1024)

typedef short short8 __attribute__((ext_vector_type(8)));
typedef float f32x4 __attribute__((ext_vector_type(4)));

__device__ __forceinline__ ushort f2b(float f) {
    union { float f; unsigned u; } v; v.f = f;
    unsigned r = v.u + 0x7fffu + ((v.u >> 16) & 1u);
    return (ushort)(r >> 16);
}
__device__ __forceinline__ float b2f(ushort u) {
    union { unsigned u; float f; } v; v.u = ((unsigned)u) << 16;
    return v.f;
}

// ---------------- small prep kernels ----------------
__global__ void pad_w_k(const float* __restrict__ W, ushort* __restrict__ Wp,
                        int N, int K, int Kp) {
    int idx = blockIdx.x * 256 + threadIdx.x;
    if (idx >= NP * Kp) return;
    int n = idx / Kp, k = idx - n * Kp;
    Wp[idx] = (n < N && k < K) ? f2b(W[n * K + k]) : (ushort)0;
}

__global__ void dest_k(const int* __restrict__ b2a, const int* __restrict__ b2revb,
                       int* __restrict__ dest) {
    int b = blockIdx.x * 256 + threadIdx.x;
    if (b < NB) dest[b] = b2a[b2revb[b]];
}

// ---------------- CSR build: cnt -> scan -> scatter ----------------
__global__ void count_k(const int* __restrict__ dest, int* __restrict__ cnt) {
    int b = blockIdx.x * 256 + threadIdx.x;
    if (b < NB) atomicAdd(&cnt[dest[b]], 1);
}

__global__ void scanA_k(const int* __restrict__ cnt, int* __restrict__ tsum) {
    __shared__ int sm[256];
    const int tid = threadIdx.x;
    int base = blockIdx.x * 1024 + tid * 4;
    int s = 0;
#pragma unroll
    for (int j = 0; j < 4; ++j) { int i = base + j; if (i < NA) s += cnt[i]; }
    sm[tid] = s; __syncthreads();
    for (int o = 128; o > 0; o >>= 1) {
        if (tid < o) sm[tid] += sm[tid + o];
        __syncthreads();
    }
    if (tid == 0) tsum[blockIdx.x] = sm[0];
}

__global__ void scanB_k(const int* __restrict__ tsum, int* __restrict__ toff,
                        int* __restrict__ rs) {
    if (threadIdx.x == 0) {
        int run = 0;
        for (int t = 0; t < NT; ++t) { toff[t] = run; run += tsum[t]; }
        rs[NA] = run;
    }
}

__global__ void scanC_k(const int* __restrict__ cnt, const int* __restrict__ toff,
                        int* __restrict__ rs) {
    __shared__ int sm[256];
    const int tid = threadIdx.x;
    int base = blockIdx.x * 1024 + tid * 4;
    int v[4]; int s = 0;
#pragma unroll
    for (int j = 0; j < 4; ++j) {
        v[j] = (base + j < NA) ? cnt[base + j] : 0;
        s += v[j];
    }
    sm[tid] = s; __syncthreads();
    for (int o = 1; o < 256; o <<= 1) {
        int x = (tid >= o) ? sm[tid - o] : 0;
        __syncthreads();
        sm[tid] += x;
        __syncthreads();
    }
    int acc = sm[tid] - s + toff[blockIdx.x];
#pragma unroll
    for (int j = 0; j < 4; ++j) {
        if (base + j < NA) rs[base + j] = acc;
        acc += v[j];
    }
}

__global__ void scatter_k(const int* __restrict__ dest, const int* __restrict__ rs,
                          int* __restrict__ cur, int* __restrict__ bl) {
    int b = blockIdx.x * 256 + threadIdx.x;
    if (b >= NB) return;
    int a = dest[b];
    int pos = rs[a] + atomicAdd(&cur[a], 1);
    bl[pos] = b;
}

// ---------------- GEMM: C = relu([self +] A @ W^T + bias) ----------------
// MODE 0: A = f_bonds fp32 [NB][BFD]          -> Cb = Hb bf16 [NB][NP]
// MODE 1: A = Mbuf bf16 [NB][NP]; self = Hb   -> Cb = Hb (in place)
// MODE 2: A = concat(f_atoms fp32 [NA][AFD], sum fp32 [NA][SMP]) -> Cf fp32 [NA][HID]
template<int MODE>
__global__ __launch_bounds__(512) void gemm_k(
    const float* __restrict__ A1, const float* __restrict__ A2,
    const ushort* __restrict__ Ab,
    const ushort* __restrict__ W, const float* __restrict__ bias,
    ushort* __restrict__ Cb, float* __restrict__ Cf,
    int Kp, int Ksteps)
{
    __shared__ ushort As[32 * 36];
    __shared__ ushort Bs[NP * 36];
    const int tid  = threadIdx.x;
    const int wave = tid >> 6, lane = tid & 63;
    const int wr = wave >> 2, wc = wave & 3;   // 2 x 4 waves
    const int g = lane >> 4, lr = lane & 15;
    const int m0 = blockIdx.x * 32;

    f32x4 acc[5];
#pragma unroll
    for (int f = 0; f < 5; ++f) acc[f] = (f32x4){0.f, 0.f, 0.f, 0.f};

    for (int ks = 0; ks < Ksteps; ++ks) {
        const int k0 = ks * 32;
        __syncthreads();
        // ---- stage A tile: 32 rows x 32 cols bf16 ----
        if (tid < 128) {
            const int row = tid >> 2, cc = (tid & 3) * 8;
            const int gm = m0 + row;
            ushort v[8];
            if (MODE == 0) {
#pragma unroll
                for (int j = 0; j < 8; ++j) {
                    int k = k0 + cc + j;
                    v[j] = (k < BFD) ? f2b(A1[(size_t)gm * BFD + k]) : (ushort)0;
                }
            } else if (MODE == 1) {
                const ushort* p = &Ab[(size_t)gm * NP + k0 + cc];
                ushort4 u0 = *(const ushort4*)p, u1 = *(const ushort4*)(p + 4);
                v[0]=u0.x; v[1]=u0.y; v[2]=u0.z; v[3]=u0.w;
                v[4]=u1.x; v[5]=u1.y; v[6]=u1.z; v[7]=u1.w;
            } else {
#pragma unroll
                for (int j = 0; j < 8; ++j) {
                    int k = k0 + cc + j;
                    float x = 0.f;
                    if (k < AFD) x = A1[(size_t)gm * AFD + k];
                    else if (k < AFD + SMP) x = A2[(size_t)gm * SMP + (k - AFD)];
                    v[j] = f2b(x);
                }
            }
            ushort* dst = &As[row * 36 + cc];
            *(ushort4*)dst       = make_ushort4(v[0], v[1], v[2], v[3]);
            *(ushort4*)(dst + 4) = make_ushort4(v[4], v[5], v[6], v[7]);
        }
        // ---- stage B tile: NP rows x 32 cols bf16 ----
        for (int idx = tid; idx < NP * 4; idx += 512) {
            const int n = idx >> 2, cc = (idx & 3) * 8;
            const ushort* p = &W[(size_t)n * Kp + k0 + cc];
            ushort4 u0 = *(const ushort4*)p, u1 = *(const ushort4*)(p + 4);
            ushort* dst = &Bs[n * 36 + cc];
            *(ushort4*)dst       = u0;
            *(ushort4*)(dst + 4) = u1;
        }
        __syncthreads();
        // ---- fragments + MFMA ----
        const ushort* ap = &As[(wr * 16 + lr) * 36 + 4 * g];
        ushort4 alo = *(const ushort4*)ap;
        ushort4 ahi = *(const ushort4*)(ap + 16);
        short8 af = {(short)alo.x, (short)alo.y, (short)alo.z, (short)alo.w,
                     (short)ahi.x, (short)ahi.y, (short)ahi.z, (short)ahi.w};
#pragma unroll
        for (int f = 0; f < 5; ++f) {
            const int col = wc * 80 + f * 16 + lr;
            const ushort* bp = &Bs[col * 36 + 4 * g];
            ushort4 blo = *(const ushort4*)bp;
            ushort4 bhi = *(const ushort4*)(bp + 16);
            short8 bfr = {(short)blo.x, (short)blo.y, (short)blo.z, (short)blo.w,
                          (short)bhi.x, (short)bhi.y, (short)bhi.z, (short)bhi.w};
            acc[f] = __builtin_amdgcn_mfma_f32_16x16x32_bf16(af, bfr, acc[f], 0, 0, 0);
        }
    }
    // ---- epilogue ----
#pragma unroll
    for (int f = 0; f < 5; ++f) {
        const int col = wc * 80 + f * 16 + lr;
        const float bv = (col < HID) ? bias[col] : 0.f;
#pragma unroll
        for (int r = 0; r < 4; ++r) {
            const int row = m0 + wr * 16 + g * 4 + r;
            float v = acc[f][r] + bv;
            if (MODE == 1) v += b2f(Cb[(size_t)row * NP + col]);
            v = fmaxf(v, 0.f);
            if (MODE == 2) {
                if (col < HID) Cf[(size_t)row * HID + col] = v;
            } else {
                Cb[(size_t)row * NP + col] = f2b(v);
            }
        }
    }
}

// ---------------- segment sum via CSR gather ----------------
// sum[a][c..c+8] = sum over bonds j in [rs[a], rs[a+1]) of Hb[bl[j]][c..c+8]
__global__ void seg_sum_csr_k(const ushort* __restrict__ Hb, const int* __restrict__ rs,
                              const int* __restrict__ bl, float* __restrict__ sum) {
    int idx = blockIdx.x * 256 + threadIdx.x;
    if (idx >= NA * 38) return;
    int a = idx / 38, c = (idx - a * 38) * 8;
    int s0 = rs[a], s1 = rs[a + 1];
    float acc[8] = {0.f, 0.f, 0.f, 0.f, 0.f, 0.f, 0.f, 0.f};
    for (int j = s0; j < s1; ++j) {
        const ushort* p = &Hb[(size_t)bl[j] * NP + c];
        ushort4 u0 = *(const ushort4*)p, u1 = *(const ushort4*)(p + 4);
        acc[0] += b2f(u0.x); acc[1] += b2f(u0.y);
        acc[2] += b2f(u0.z); acc[3] += b2f(u0.w);
        acc[4] += b2f(u1.x); acc[5] += b2f(u1.y);
        acc[6] += b2f(u1.z); acc[7] += b2f(u1.w);
    }
    float* dst = &sum[(size_t)a * SMP + c];
    *(float4*)dst       = make_float4(acc[0], acc[1], acc[2], acc[3]);
    *(float4*)(dst + 4) = make_float4(acc[4], acc[5], acc[6], acc[7]);
}

// ---------------- Mbuf[b][:] = bf16(sum[b2a[b]][:] - Hb[b2revb[b]][:]) ----------------
__global__ void gather_k(const float* __restrict__ sum, const ushort* __restrict__ Hb,
                         const int* __restrict__ b2a, const int* __restrict__ b2revb,
                         ushort* __restrict__ Mb) {
    int idx = blockIdx.x * 256 + threadIdx.x;
    if (idx >= NB * 40) return;
    int b = idx / 40, c = (idx - b * 40) * 8;
    ushort4 o0 = make_ushort4(0, 0, 0, 0), o1 = o0;
    if (c < SMP) {
        int sa = b2a[b], rb = b2revb[b];
        const float* sp = &sum[(size_t)sa * SMP + c];
        const ushort* hp = &Hb[(size_t)rb * NP + c];
        ushort4 h0 = *(const ushort4*)hp, h1 = *(const ushort4*)(hp + 4);
        o0 = make_ushort4(f2b(sp[0] - b2f(h0.x)), f2b(sp[1] - b2f(h0.y)),
                          f2b(sp[2] - b2f(h0.z)), f2b(sp[3] - b2f(h0.w)));
        o1 = make_ushort4(f2b(sp[4] - b2f(h1.x)), f2b(sp[5] - b2f(h1.y)),
                          f2b(sp[6] - b2f(h1.z)), f2b(sp[7] - b2f(h1.w)));
    }
    ushort* dp = &Mb[(size_t)b * NP + c];
    *(ushort4*)dp       = o0;
    *(ushort4*)(dp + 4) = o1;
}

// ---------------- final: d_out H_bonds fp32 <- Hb bf16 ----------------
__global__ void conv_k(const ushort* __restrict__ Hb, float* __restrict__ out) {
    int idx = blockIdx.x * 256 + threadIdx.x;
    if (idx >= NB * 75) return;
    int b = idx / 75, c = (idx - b * 75) * 4;
    ushort4 u = *(const ushort4*)&Hb[(size_t)b * NP + c];
    float4 v = make_float4(b2f(u.x), b2f(u.y), b2f(u.z), b2f(u.w));
    *(float4*)&out[(size_t)b * HID + c] = v;
}

extern "C" void kernel_launch(void* const* d_in, const int* in_sizes, int n_in,
                              void* d_out, int out_size, void* d_ws, size_t ws_size,
                              hipStream_t stream) {
    const float* f_atoms = (const float*)d_in[0];
    const float* f_bonds = (const float*)d_in[1];
    const int*   b2a     = (const int*)d_in[2];
    const int*   b2revb  = (const int*)d_in[3];
    const float* Wi_w    = (const float*)d_in[4];
    const float* Wi_b    = (const float*)d_in[5];
    const float* Wh_w    = (const float*)d_in[6];
    const float* Wh_b    = (const float*)d_in[7];
    const float* Wo_w    = (const float*)d_in[8];
    const float* Wo_b    = (const float*)d_in[9];
    float* out = (float*)d_out;

    // workspace layout
    char* ws = (char*)d_ws;
    ushort* Hb   = (ushort*)ws;            ws += (size_t)NB * NP * 2;   // 256.0 MB
    float*  sum  = (float*)ws;             ws += (size_t)NA * SMP * 4;  // 121.6 MB
    int*    dest = (int*)ws;               ws += (size_t)NB * 4;        // 1.6 MB
    ushort* Wip  = (ushort*)ws;            ws += (size_t)NP * 160 * 2;
    ushort* Whp  = (ushort*)ws;            ws += (size_t)NP * NP * 2;
    ushort* Wop  = (ushort*)ws;            ws += (size_t)NP * 448 * 2;
    int*    cnt  = (int*)ws;               ws += (size_t)NA * 4;
    int*    cur  = (int*)ws;               ws += (size_t)NA * 4;
    int*    rs   = (int*)ws;               ws += (size_t)(NA + 1) * 4;
    int*    bl   = (int*)ws;               ws += (size_t)NB * 4;
    int*    tsum = (int*)ws;               ws += 128 * 4;
    int*    toff = (int*)ws;               ws += 128 * 4;
    // msgs buffer lives inside d_out's H_bonds region (overwritten at the end)
    float* Hatoms = out;                   // [NA][HID]
    float* Hbonds = out + (size_t)NA * HID;
    ushort* Mbuf  = (ushort*)Hbonds;       // [NB][NP] bf16 (256 MB of 480 MB)

    // prep: weights + dest
    pad_w_k<<<(NP * 160 + 255) / 256, 256, 0, stream>>>(Wi_w, Wip, HID, BFD, 160);
    pad_w_k<<<(NP * NP  + 255) / 256, 256, 0, stream>>>(Wh_w, Whp, HID, HID, NP);
    pad_w_k<<<(NP * 448 + 255) / 256, 256, 0, stream>>>(Wo_w, Wop, HID, AFD + HID, 448);
    dest_k<<<(NB + 255) / 256, 256, 0, stream>>>(b2a, b2revb, dest);

    // prep: CSR of dest (built once; shared by all 3 segment sums)
    hipMemsetAsync(cnt, 0, (size_t)NA * 4, stream);
    hipMemsetAsync(cur, 0, (size_t)NA * 4, stream);
    count_k<<<(NB + 255) / 256, 256, 0, stream>>>(dest, cnt);
    scanA_k<<<NT, 256, 0, stream>>>(cnt, tsum);
    scanB_k<<<1, 64, 0, stream>>>(tsum, toff, rs);
    scanC_k<<<NT, 256, 0, stream>>>(cnt, toff, rs);
    scatter_k<<<(NB + 255) / 256, 256, 0, stream>>>(dest, rs, cur, bl);

    // H_bonds = relu(f_bonds @ Wi^T + bi)
    gemm_k<0><<<NB / 32, 512, 0, stream>>>(f_bonds, nullptr, nullptr, Wip, Wi_b,
                                           Hb, nullptr, 160, 5);

    for (int it = 0; it < 2; ++it) {
        seg_sum_csr_k<<<(NA * 38 + 255) / 256, 256, 0, stream>>>(Hb, rs, bl, sum);
        gather_k<<<(NB * 40 + 255) / 256, 256, 0, stream>>>(sum, Hb, b2a, b2revb, Mbuf);
        gemm_k<1><<<NB / 32, 512, 0, stream>>>(nullptr, nullptr, Mbuf, Whp, Wh_b,
                                               Hb, nullptr, NP, 10);
    }

    seg_sum_csr_k<<<(NA * 38 + 255) / 256, 256, 0, stream>>>(Hb, rs, bl, sum);

    // H_atoms = relu(concat(f_atoms, sum) @ Wo^T + bo)
    gemm_k<2><<<NA / 32, 512, 0, stream>>>(f_atoms, sum, nullptr, Wop, Wo_b,
                                           nullptr, Hatoms, 448, 14);

    // H_bonds fp32 out (overwrites Mbuf region)
    conv_k<<<(NB * 75 + 255) / 256, 256, 0, stream>>>(Hb, Hbonds);
}

// Round 3
// 1724.133 us; speedup vs baseline: 6.7070x; 1.1354x over previous
//
#include <hip/hip_runtime.h>
#include <hip/hip_bf16.h>

// ---------------- problem constants ----------------
#define NB 400000     // n_bonds
#define NA 100000     // n_atoms
#define AFD 133       // atom feature dim
#define BFD 147       // bond feature dim
#define HID 300       // hidden
#define NP  320       // padded hidden (output cols of every GEMM)
#define SMP 304       // sum_msgs padded cols
#define NT  98        // scan tiles: ceil(NA/1024)

typedef short short8 __attribute__((ext_vector_type(8)));
typedef float f32x4 __attribute__((ext_vector_type(4)));

__device__ __forceinline__ ushort f2b(float f) {
    union { float f; unsigned u; } v; v.f = f;
    unsigned r = v.u + 0x7fffu + ((v.u >> 16) & 1u);
    return (ushort)(r >> 16);
}
__device__ __forceinline__ float b2f(ushort u) {
    union { unsigned u; float f; } v; v.u = ((unsigned)u) << 16;
    return v.f;
}

// global_load_lds: per-lane global src (16B), wave-uniform LDS base + lane*16
#define GLDS(gp, lp) __builtin_amdgcn_global_load_lds( \
    (const __attribute__((address_space(1))) void*)(gp), \
    (__attribute__((address_space(3))) void*)(lp), 16, 0, 0)

// Permuted-k layout: within each 32-k block, granule g (16B) holds natural ks
// {4g..4g+3, 16+4g..16+4g+3}; stored granule gp = g ^ ((row>>1)&3).
// Both GEMM operands use the same map -> dot product unchanged (k-symmetry).

// ---------------- weight prep: [tiles][320 rows][32 ushorts] permuted ----------------
__global__ void pad_w_k(const float* __restrict__ W, ushort* __restrict__ Wp,
                        int N, int K, int Kp) {
    int idx = blockIdx.x * 256 + threadIdx.x;
    if (idx >= NP * Kp) return;
    int n = idx / Kp, k = idx - n * Kp;
    int t = k >> 5, kk = k & 31;
    int g = (kk & 15) >> 2, slot = (kk & 3) + ((kk >> 4) << 2);
    int gp = g ^ ((n >> 1) & 3);
    ushort v = (n < N && k < K) ? f2b(W[n * K + k]) : (ushort)0;
    Wp[(size_t)t * 10240 + n * 32 + gp * 8 + slot] = v;
}

__global__ void dest_k(const int* __restrict__ b2a, const int* __restrict__ b2revb,
                       int* __restrict__ dest) {
    int b = blockIdx.x * 256 + threadIdx.x;
    if (b < NB) dest[b] = b2a[b2revb[b]];
}

// ---------------- CSR build: cnt -> scan -> scatter ----------------
__global__ void count_k(const int* __restrict__ dest, int* __restrict__ cnt) {
    int b = blockIdx.x * 256 + threadIdx.x;
    if (b < NB) atomicAdd(&cnt[dest[b]], 1);
}

__global__ void scanA_k(const int* __restrict__ cnt, int* __restrict__ tsum) {
    __shared__ int sm[256];
    const int tid = threadIdx.x;
    int base = blockIdx.x * 1024 + tid * 4;
    int s = 0;
#pragma unroll
    for (int j = 0; j < 4; ++j) { int i = base + j; if (i < NA) s += cnt[i]; }
    sm[tid] = s; __syncthreads();
    for (int o = 128; o > 0; o >>= 1) {
        if (tid < o) sm[tid] += sm[tid + o];
        __syncthreads();
    }
    if (tid == 0) tsum[blockIdx.x] = sm[0];
}

__global__ void scanB_k(const int* __restrict__ tsum, int* __restrict__ toff,
                        int* __restrict__ rs) {
    if (threadIdx.x == 0) {
        int run = 0;
        for (int t = 0; t < NT; ++t) { toff[t] = run; run += tsum[t]; }
        rs[NA] = run;
    }
}

__global__ void scanC_k(const int* __restrict__ cnt, const int* __restrict__ toff,
                        int* __restrict__ rs) {
    __shared__ int sm[256];
    const int tid = threadIdx.x;
    int base = blockIdx.x * 1024 + tid * 4;
    int v[4]; int s = 0;
#pragma unroll
    for (int j = 0; j < 4; ++j) {
        v[j] = (base + j < NA) ? cnt[base + j] : 0;
        s += v[j];
    }
    sm[tid] = s; __syncthreads();
    for (int o = 1; o < 256; o <<= 1) {
        int x = (tid >= o) ? sm[tid - o] : 0;
        __syncthreads();
        sm[tid] += x;
        __syncthreads();
    }
    int acc = sm[tid] - s + toff[blockIdx.x];
#pragma unroll
    for (int j = 0; j < 4; ++j) {
        if (base + j < NA) rs[base + j] = acc;
        acc += v[j];
    }
}

__global__ void scatter_k(const int* __restrict__ dest, const int* __restrict__ rs,
                          int* __restrict__ cur, int* __restrict__ bl) {
    int b = blockIdx.x * 256 + threadIdx.x;
    if (b >= NB) return;
    int a = dest[b];
    int pos = rs[a] + atomicAdd(&cur[a], 1);
    bl[pos] = b;
}

// ---------------- A prep: f_bonds fp32 -> Ab0 bf16 [NB][160] permuted ----------------
__global__ void cvt0_k(const float* __restrict__ fb, ushort* __restrict__ Ab) {
    int idx = blockIdx.x * 256 + threadIdx.x;
    if (idx >= NB * 20) return;
    int b = idx / 20, p = idx - b * 20;
    int t = p >> 2, gp = p & 3;
    int g = gp ^ ((b >> 1) & 3);
    int k0 = t * 32 + 4 * g, k1 = k0 + 16;
    const float* src = fb + (size_t)b * BFD;
    ushort o[8];
#pragma unroll
    for (int s = 0; s < 4; ++s) o[s]     = (k0 + s < BFD) ? f2b(src[k0 + s]) : (ushort)0;
#pragma unroll
    for (int s = 0; s < 4; ++s) o[4 + s] = (k1 + s < BFD) ? f2b(src[k1 + s]) : (ushort)0;
    ushort* dst = &Ab[(size_t)b * 160 + t * 32 + gp * 8];
    *(ushort4*)dst       = make_ushort4(o[0], o[1], o[2], o[3]);
    *(ushort4*)(dst + 4) = make_ushort4(o[4], o[5], o[6], o[7]);
}

// ---------------- Mbuf[b] = bf16(sum[b2a[b]] - Hb[b2revb[b]]), permuted ----------------
__global__ void gather_k(const float* __restrict__ sum, const ushort* __restrict__ Hb,
                         const int* __restrict__ b2a, const int* __restrict__ b2revb,
                         ushort* __restrict__ Mb) {
    int idx = blockIdx.x * 256 + threadIdx.x;
    if (idx >= NB * 40) return;
    int b = idx / 40, p = idx - b * 40;
    int t = p >> 2, gp = p & 3;
    int g = gp ^ ((b >> 1) & 3);
    int k0 = t * 32 + 4 * g, k1 = k0 + 16;
    int sa = b2a[b], rb = b2revb[b];
    const float* sp = &sum[(size_t)sa * SMP];
    const ushort* hp = &Hb[(size_t)rb * NP];
    float4 s0 = *(const float4*)&sp[k0];                    // k0+3 <= 303 always
    float4 s1 = (k1 < SMP) ? *(const float4*)&sp[k1] : make_float4(0.f, 0.f, 0.f, 0.f);
    ushort4 h0 = *(const ushort4*)&hp[k0];
    ushort4 h1 = *(const ushort4*)&hp[k1];
    ushort* dst = &Mb[(size_t)b * NP + t * 32 + gp * 8];
    *(ushort4*)dst       = make_ushort4(f2b(s0.x - b2f(h0.x)), f2b(s0.y - b2f(h0.y)),
                                        f2b(s0.z - b2f(h0.z)), f2b(s0.w - b2f(h0.w)));
    *(ushort4*)(dst + 4) = make_ushort4(f2b(s1.x - b2f(h1.x)), f2b(s1.y - b2f(h1.y)),
                                        f2b(s1.z - b2f(h1.z)), f2b(s1.w - b2f(h1.w)));
}

// ---------------- concat(f_atoms, sum) -> Ac bf16 [NA][448] permuted ----------------
__global__ void cat2_k(const float* __restrict__ fa, const float* __restrict__ sum,
                       ushort* __restrict__ Ac) {
    int idx = blockIdx.x * 256 + threadIdx.x;
    if (idx >= NA * 56) return;
    int a = idx / 56, p = idx - a * 56;
    int t = p >> 2, gp = p & 3;
    int g = gp ^ ((a >> 1) & 3);
    ushort o[8];
#pragma unroll
    for (int e = 0; e < 8; ++e) {
        int k = t * 32 + 4 * g + (e & 3) + ((e >> 2) << 4);
        float x = 0.f;
        if (k < AFD) x = fa[(size_t)a * AFD + k];
        else if (k < AFD + HID) x = sum[(size_t)a * SMP + (k - AFD)];
        o[e] = f2b(x);
    }
    ushort* dst = &Ac[(size_t)a * 448 + t * 32 + gp * 8];
    *(ushort4*)dst       = make_ushort4(o[0], o[1], o[2], o[3]);
    *(ushort4*)(dst + 4) = make_ushort4(o[4], o[5], o[6], o[7]);
}

// ---------------- GEMM: C = relu([self +] A @ W^T + bias) ----------------
// BM=128, BN=320, BK=32. 8 waves as 2(M) x 4(N); wave tile 64x80 = acc[4][5].
// A: bf16 [M][Kp] permuted; W: [Ksteps][320][32] permuted. glds staging.
// MODE 0: -> Cb bf16.  MODE 1: self-add from Cb, in-place.  MODE 2: -> Cf fp32.
template<int MODE>
__global__ __launch_bounds__(512) void gemm_k(
    const ushort* __restrict__ Asrc, const ushort* __restrict__ W,
    const float* __restrict__ bias, ushort* __restrict__ Cb,
    float* __restrict__ Cf, int Kp, int Ksteps, int M)
{
    __shared__ ushort As[128 * 32];
    __shared__ ushort Bs[320 * 32];
    const int tid = threadIdx.x;
    const int w = tid >> 6, lane = tid & 63;
    const int wr = w >> 2, wc = w & 3;
    const int g = lane >> 4, lr = lane & 15;
    const int swz = (lr >> 1) & 3;
    const int m0 = blockIdx.x * 128;

    // A staging: wave w stages rows [w*16, w*16+16), one 16B granule per lane
    int arow = m0 + w * 16 + (lane >> 2);
    if (MODE == 2 && arow >= M) arow = M - 1;
    const ushort* aglob = Asrc + (size_t)arow * Kp + (lane & 3) * 8;
    ushort* alds = &As[w * 512];

    f32x4 acc[4][5];
#pragma unroll
    for (int mi = 0; mi < 4; ++mi)
#pragma unroll
        for (int ni = 0; ni < 5; ++ni) acc[mi][ni] = (f32x4){0.f, 0.f, 0.f, 0.f};

    for (int t = 0; t < Ksteps; ++t) {
        __syncthreads();
        // stage A (1 glds/wave) + B (2.5 glds/wave)
        GLDS(aglob + t * 32, alds);
        const ushort* wt = W + (size_t)t * 10240;
        GLDS(wt + (size_t)w * 512 + lane * 8,        &Bs[w * 512]);
        GLDS(wt + (size_t)(w + 8) * 512 + lane * 8,  &Bs[(w + 8) * 512]);
        if (w < 4)
            GLDS(wt + (size_t)(w + 16) * 512 + lane * 8, &Bs[(w + 16) * 512]);
        __syncthreads();
        // fragments (single b128 each) + MFMA
        short8 af[4];
#pragma unroll
        for (int mi = 0; mi < 4; ++mi) {
            int r = wr * 64 + mi * 16 + lr;
            af[mi] = *(const short8*)&As[r * 32 + ((g ^ swz) << 3)];
        }
#pragma unroll
        for (int ni = 0; ni < 5; ++ni) {
            int c = wc * 80 + ni * 16 + lr;
            short8 bf = *(const short8*)&Bs[c * 32 + ((g ^ swz) << 3)];
#pragma unroll
            for (int mi = 0; mi < 4; ++mi)
                acc[mi][ni] = __builtin_amdgcn_mfma_f32_16x16x32_bf16(af[mi], bf, acc[mi][ni], 0, 0, 0);
        }
    }
    // ---- epilogue: C row = m0 + wr*64 + mi*16 + g*4 + r, col = wc*80 + ni*16 + lr ----
#pragma unroll
    for (int ni = 0; ni < 5; ++ni) {
        const int col = wc * 80 + ni * 16 + lr;
        const float bv = (col < HID) ? bias[col] : 0.f;
#pragma unroll
        for (int mi = 0; mi < 4; ++mi) {
            const int row = m0 + wr * 64 + mi * 16 + g * 4;
#pragma unroll
            for (int r = 0; r < 4; ++r) {
                float v = acc[mi][ni][r] + bv;
                size_t off = (size_t)(row + r) * NP + col;
                if (MODE == 1) v += b2f(Cb[off]);
                v = fmaxf(v, 0.f);
                if (MODE == 2) {
                    if (col < HID && row + r < M) Cf[(size_t)(row + r) * HID + col] = v;
                } else {
                    Cb[off] = f2b(v);
                }
            }
        }
    }
}

// ---------------- segment sum via CSR gather (Hb natural layout) ----------------
__global__ void seg_sum_csr_k(const ushort* __restrict__ Hb, const int* __restrict__ rs,
                              const int* __restrict__ bl, float* __restrict__ sum) {
    int idx = blockIdx.x * 256 + threadIdx.x;
    if (idx >= NA * 38) return;
    int a = idx / 38, c = (idx - a * 38) * 8;
    int s0 = rs[a], s1 = rs[a + 1];
    float acc[8] = {0.f, 0.f, 0.f, 0.f, 0.f, 0.f, 0.f, 0.f};
    for (int j = s0; j < s1; ++j) {
        const ushort* p = &Hb[(size_t)bl[j] * NP + c];
        ushort4 u0 = *(const ushort4*)p, u1 = *(const ushort4*)(p + 4);
        acc[0] += b2f(u0.x); acc[1] += b2f(u0.y);
        acc[2] += b2f(u0.z); acc[3] += b2f(u0.w);
        acc[4] += b2f(u1.x); acc[5] += b2f(u1.y);
        acc[6] += b2f(u1.z); acc[7] += b2f(u1.w);
    }
    float* dst = &sum[(size_t)a * SMP + c];
    *(float4*)dst       = make_float4(acc[0], acc[1], acc[2], acc[3]);
    *(float4*)(dst + 4) = make_float4(acc[4], acc[5], acc[6], acc[7]);
}

// ---------------- final: d_out H_bonds fp32 <- Hb bf16 ----------------
__global__ void conv_k(const ushort* __restrict__ Hb, float* __restrict__ out) {
    int idx = blockIdx.x * 256 + threadIdx.x;
    if (idx >= NB * 75) return;
    int b = idx / 75, c = (idx - b * 75) * 4;
    ushort4 u = *(const ushort4*)&Hb[(size_t)b * NP + c];
    float4 v = make_float4(b2f(u.x), b2f(u.y), b2f(u.z), b2f(u.w));
    *(float4*)&out[(size_t)b * HID + c] = v;
}

extern "C" void kernel_launch(void* const* d_in, const int* in_sizes, int n_in,
                              void* d_out, int out_size, void* d_ws, size_t ws_size,
                              hipStream_t stream) {
    const float* f_atoms = (const float*)d_in[0];
    const float* f_bonds = (const float*)d_in[1];
    const int*   b2a     = (const int*)d_in[2];
    const int*   b2revb  = (const int*)d_in[3];
    const float* Wi_w    = (const float*)d_in[4];
    const float* Wi_b    = (const float*)d_in[5];
    const float* Wh_w    = (const float*)d_in[6];
    const float* Wh_b    = (const float*)d_in[7];
    const float* Wo_w    = (const float*)d_in[8];
    const float* Wo_b    = (const float*)d_in[9];
    float* out = (float*)d_out;

    // workspace layout (~384 MB, same budget as the passing R2 version)
    char* ws = (char*)d_ws;
    ushort* Hb   = (ushort*)ws;            ws += (size_t)NB * NP * 2;   // 256.0 MB
    float*  sum  = (float*)ws;             ws += (size_t)NA * SMP * 4;  // 121.6 MB
    int*    dest = (int*)ws;               ws += (size_t)NB * 4;        // 1.6 MB
    ushort* Wp0  = (ushort*)ws;            ws += (size_t)5  * 10240 * 2;
    ushort* Wp1  = (ushort*)ws;            ws += (size_t)10 * 10240 * 2;
    ushort* Wp2  = (ushort*)ws;            ws += (size_t)14 * 10240 * 2;
    int*    cnt  = (int*)ws;               ws += (size_t)NA * 4;
    int*    cur  = (int*)ws;               ws += (size_t)NA * 4;
    int*    rs   = (int*)ws;               ws += (size_t)(NA + 1) * 4;
    int*    bl   = (int*)ws;               ws += (size_t)NB * 4;
    int*    tsum = (int*)ws;               ws += 128 * 4;
    int*    toff = (int*)ws;               ws += 128 * 4;
    // scratch inside d_out's H_bonds region (all dead before conv_k overwrites)
    float* Hatoms = out;                   // [NA][HID]
    float* Hbonds = out + (size_t)NA * HID;          // 480 MB region
    ushort* Mbuf  = (ushort*)Hbonds;                 // [NB][NP] bf16, first 256 MB
    ushort* Ab0   = (ushort*)((char*)Hbonds + (size_t)NB * NP * 2);  // next 128 MB
    ushort* Ac2   = Ab0;                             // reused after Ab0 is dead

    // prep: permuted weights + dest + CSR
    pad_w_k<<<(NP * 160 + 255) / 256, 256, 0, stream>>>(Wi_w, Wp0, HID, BFD, 160);
    pad_w_k<<<(NP * NP  + 255) / 256, 256, 0, stream>>>(Wh_w, Wp1, HID, HID, NP);
    pad_w_k<<<(NP * 448 + 255) / 256, 256, 0, stream>>>(Wo_w, Wp2, HID, AFD + HID, 448);
    dest_k<<<(NB + 255) / 256, 256, 0, stream>>>(b2a, b2revb, dest);
    hipMemsetAsync(cnt, 0, (size_t)NA * 4, stream);
    hipMemsetAsync(cur, 0, (size_t)NA * 4, stream);
    count_k<<<(NB + 255) / 256, 256, 0, stream>>>(dest, cnt);
    scanA_k<<<NT, 256, 0, stream>>>(cnt, tsum);
    scanB_k<<<1, 64, 0, stream>>>(tsum, toff, rs);
    scanC_k<<<NT, 256, 0, stream>>>(cnt, toff, rs);
    scatter_k<<<(NB + 255) / 256, 256, 0, stream>>>(dest, rs, cur, bl);

    // A0 = bf16-permuted f_bonds; H_bonds = relu(A0 @ Wi^T + bi)
    cvt0_k<<<(NB * 20 + 255) / 256, 256, 0, stream>>>(f_bonds, Ab0);
    gemm_k<0><<<NB / 128, 512, 0, stream>>>(Ab0, Wp0, Wi_b, Hb, nullptr, 160, 5, NB);

    for (int it = 0; it < 2; ++it) {
        seg_sum_csr_k<<<(NA * 38 + 255) / 256, 256, 0, stream>>>(Hb, rs, bl, sum);
        gather_k<<<(NB * 40 + 255) / 256, 256, 0, stream>>>(sum, Hb, b2a, b2revb, Mbuf);
        gemm_k<1><<<NB / 128, 512, 0, stream>>>(Mbuf, Wp1, Wh_b, Hb, nullptr, NP, 10, NB);
    }

    seg_sum_csr_k<<<(NA * 38 + 255) / 256, 256, 0, stream>>>(Hb, rs, bl, sum);

    // H_atoms = relu(concat(f_atoms, sum) @ Wo^T + bo)
    cat2_k<<<(NA * 56 + 255) / 256, 256, 0, stream>>>(f_atoms, sum, Ac2);
    gemm_k<2><<<(NA + 127) / 128, 512, 0, stream>>>(Ac2, Wp2, Wo_b, nullptr, Hatoms, 448, 14, NA);

    // H_bonds fp32 out (overwrites Mbuf/Ac2 region)
    conv_k<<<(NB * 75 + 255) / 256, 256, 0, stream>>>(Hb, Hbonds);
}